// Round 7
// baseline (5283.409 us; speedup 1.0000x reference)
//
#include <hip/hip_runtime.h>
#include <cstdint>

typedef unsigned short u16;
#define S4 4194304     // B*T*C = 4*1024*1024
#define WLEN 1048576   // C*C

// ---- workspace layout (bytes), all f32 ----
#define OFF_SR  0                   // 4096*16*4 = 256KB
#define OFF_G   262144              // 7 * S4 * 4 = 117,440,512
#define OFF_Y   117702656           // S4*4 = 16,777,216
#define OFF_YG  134479872           // S4*4 = 16,777,216
#define WS_NEED 151257088ull

__device__ __forceinline__ float sigm(float x) { return 1.f / (1.f + expf(-x)); }

// ---------------- fallback: zero y (signature absmax == 3.0625 exactly) ----------------
__global__ void k_fill0(float* __restrict__ out) {
  out[(size_t)blockIdx.x * 256 + threadIdx.x] = 0.f;
}

// ---------------- v_first passthrough (output 1), f32 ----------------
__global__ void k_copy_vf(const float4* __restrict__ src, float4* __restrict__ dst) {
  size_t i = (size_t)blockIdx.x * 256 + threadIdx.x;  // 4096*256 = 1M float4 = S4 floats
  dst[i] = src[i];
}

// ---------------- f32 GEMM: C[bt,d] = sum_c A[bt,c] * W[d,c]; optional fused time-shift mix ----
// SHIFT=1: A[bt,c] := x[bt,c] + (x[bt-1,c] - x[bt,c]) * coef[c], with x[b,t=-1]=0.
// Textbook 16x16 LDS tiling; exact by construction (plain loads, f32 FMA).
template <int SHIFT>
__global__ __launch_bounds__(256) void k_gemmf(const float* __restrict__ A0,
                                               const float* __restrict__ coef,
                                               const float* __restrict__ W,
                                               float* __restrict__ Cout) {
  __shared__ float As[16][17];
  __shared__ float Ws[16][17];
  const int tx = threadIdx.x & 15, ty = threadIdx.x >> 4;
  const int r0 = blockIdx.y * 16, c0 = blockIdx.x * 16;
  const int arow = r0 + ty;   // bt row for A load
  const int wrow = c0 + ty;   // d row for W load
  float acc = 0.f;
  for (int k0 = 0; k0 < 1024; k0 += 16) {
    float av = A0[(size_t)arow * 1024 + k0 + tx];
    if constexpr (SHIFT) {
      const int t = arow & 1023;  // arow = b*1024 + t
      float px = (t > 0) ? A0[(size_t)(arow - 1) * 1024 + k0 + tx] : 0.f;
      av = fmaf(px - av, coef[k0 + tx], av);
    }
    As[ty][tx] = av;
    Ws[ty][tx] = W[(size_t)wrow * 1024 + k0 + tx];
    __syncthreads();
    #pragma unroll
    for (int kk = 0; kk < 16; ++kk)
      acc = fmaf(As[ty][kk], Ws[tx][kk], acc);
    __syncthreads();
  }
  Cout[(size_t)(r0 + ty) * 1024 + c0 + tx] = acc;
}

// ---------------- elementwise post-projection; params read directly from d_in (f32) -------
// G slots in : 0:r 1:w-pre 2:k-raw 3:v 4:Wv1-proj 5:Wa1-proj 6:Wg1-proj
// G slots out: 0:r 1:w(decay) 2:k_final 3:v_final 4:-kk*a 5:kk 6:g
__launch_bounds__(256) __global__
void k_elem(float* __restrict__ G,
            const float* __restrict__ vf, const float* __restrict__ w0, const float* __restrict__ w2,
            const float* __restrict__ a0, const float* __restrict__ a2, const float* __restrict__ v0,
            const float* __restrict__ v2, const float* __restrict__ g2, const float* __restrict__ pkk,
            const float* __restrict__ pka, const float* __restrict__ prk, float* __restrict__ SR) {
  const int wid = blockIdx.x * 4 + (threadIdx.x >> 6);
  const int lane = threadIdx.x & 63;
  const int bt = wid >> 4, h = wid & 15;
  const int c = h * 64 + lane;
  const size_t ix = (size_t)bt * 1024 + c;
  float r = G[ix];
  // decay: w = exp(clip(-softplus(-(w0 + tanh(proj)*w2)) - 0.5, -10, 0))
  float wpre = fmaf(tanhf(G[(size_t)S4 + ix]), w2[c], w0[c]);
  float zz = -log1pf(expf(-wpre)) - 0.5f;
  zz = fminf(fmaxf(zz, -10.f), 0.f);
  G[(size_t)S4 + ix] = expf(zz);
  float k = G[2 * (size_t)S4 + ix];
  float v = G[3 * (size_t)S4 + ix];
  float a = sigm(fmaf(G[5 * (size_t)S4 + ix], a2[c], a0[c]));
  float lam = sigm(fmaf(G[4 * (size_t)S4 + ix], v2[c], v0[c]));
  float vfin = fmaf(vf[ix] - v, lam, v);          // v + (v_first - v)*sigmoid(...)
  G[3 * (size_t)S4 + ix] = vfin;
  G[6 * (size_t)S4 + ix] = sigm(G[6 * (size_t)S4 + ix]) * g2[c];
  float kk = k * pkk[c];                           // raw k * k_k
  float n2 = kk * kk;
  #pragma unroll
  for (int m = 1; m < 64; m <<= 1) n2 += __shfl_xor(n2, m);
  float kkn = kk / fmaxf(sqrtf(n2), 1e-12f);       // unit-norm per (b,t,h)
  G[5 * (size_t)S4 + ix] = kkn;
  float kf = k * fmaf(a - 1.f, pka[c], 1.f);       // k*(1+(a-1)*k_a)
  G[2 * (size_t)S4 + ix] = kf;
  G[4 * (size_t)S4 + ix] = -kkn * a;
  float sp = r * kf * prk[c];                      // (r*k*r_k) partial
  #pragma unroll
  for (int m = 1; m < 64; m <<= 1) sp += __shfl_xor(sp, m);
  if (lane == 0) SR[(size_t)bt * 16 + h] = sp;
}

// ---------------- sequential scan: 1 wave = 16 state-rows of one (b,h) --------------------
// lane = (q, i15): i = rb*16 + (lane&15); j-quadrant q = lane>>4 covers j = q*16+e.
// s[i,j] = s[i,j]*w[i] + (sum_k s[i,k]*kk[k])*(-kk[j]a[j]) + v[i]*k[j];  y[i] = sum_j s[i,j]r[j]
__global__ __launch_bounds__(64) void k_scan(const float* __restrict__ G, float* __restrict__ Y) {
  const int bh = blockIdx.x >> 2, rb = blockIdx.x & 3;
  const int b = bh >> 4, h = bh & 15;
  const int lane = threadIdx.x;
  const int i15 = lane & 15, q = lane >> 4;
  const int iw = rb * 16 + i15;
  const int jb = q * 16;
  const size_t gb = (size_t)b * 1048576 + h * 64;
  const float* R  = G;
  const float* Wd = G + 1 * (size_t)S4;
  const float* K  = G + 2 * (size_t)S4;
  const float* V  = G + 3 * (size_t)S4;
  const float* NK = G + 4 * (size_t)S4;
  const float* KK = G + 5 * (size_t)S4;
  float s[16];
  #pragma unroll
  for (int e = 0; e < 16; ++e) s[e] = 0.f;
  for (int t = 0; t < 1024; ++t) {
    const size_t ro = gb + (size_t)t * 1024;
    float kf[16], nk[16], kn[16], rf[16];
    #pragma unroll
    for (int q4 = 0; q4 < 4; ++q4) {
      *(float4*)(kf + q4 * 4) = *(const float4*)(K  + ro + jb + q4 * 4);
      *(float4*)(nk + q4 * 4) = *(const float4*)(NK + ro + jb + q4 * 4);
      *(float4*)(kn + q4 * 4) = *(const float4*)(KK + ro + jb + q4 * 4);
      *(float4*)(rf + q4 * 4) = *(const float4*)(R  + ro + jb + q4 * 4);
    }
    const float wv = Wd[ro + iw];
    const float vv = V[ro + iw];
    float sab = 0.f;
    #pragma unroll
    for (int e = 0; e < 16; ++e) sab = fmaf(s[e], kn[e], sab);
    sab += __shfl_xor(sab, 16);
    sab += __shfl_xor(sab, 32);
    float yp = 0.f;
    #pragma unroll
    for (int e = 0; e < 16; ++e) {
      s[e] = fmaf(s[e], wv, fmaf(vv, kf[e], sab * nk[e]));
      yp = fmaf(s[e], rf[e], yp);
    }
    yp += __shfl_xor(yp, 16);
    yp += __shfl_xor(yp, 32);
    if (q == 0) Y[((size_t)bh * 1024 + t) * 64 + iw] = yp;
  }
}

// ---------------- GroupNorm + (r·k·r_k)·v residual + g gate -> f32 Yg ---------------------
__global__ __launch_bounds__(256) void k_post(const float* __restrict__ Y, const float* __restrict__ G,
                                              const float* __restrict__ lnw, const float* __restrict__ lnb,
                                              const float* __restrict__ SR, float* __restrict__ Yg) {
  const int gid = blockIdx.x * 4 + (threadIdx.x >> 6);  // bh*1024 + t
  const int lane = threadIdx.x & 63;
  const int bh = gid >> 10, t = gid & 1023;
  const int b = bh >> 4, h = bh & 15;
  float y = Y[(size_t)gid * 64 + lane];
  float s1 = y, s2 = y * y;
  #pragma unroll
  for (int m = 1; m < 64; m <<= 1) { s1 += __shfl_xor(s1, m); s2 += __shfl_xor(s2, m); }
  float mu = s1 * 0.015625f;
  float var = s2 * 0.015625f - mu * mu;
  float inv = rsqrtf(var + 0.00064f);
  const int c = h * 64 + lane;
  const size_t bt = (size_t)b * 1024 + t;
  float yn = fmaf((y - mu) * inv, lnw[c], lnb[c]);
  float res = fmaf(SR[bt * 16 + h], G[3 * (size_t)S4 + bt * 1024 + c], yn);
  Yg[bt * 1024 + c] = res * G[6 * (size_t)S4 + bt * 1024 + c];
}

extern "C" void kernel_launch(void* const* d_in, const int* in_sizes, int n_in,
                              void* d_out, int out_size, void* d_ws, size_t ws_size,
                              hipStream_t stream) {
  // output 1 = v_first passthrough (f32), always
  k_copy_vf<<<4096, 256, 0, stream>>>((const float4*)d_in[1], (float4*)((float*)d_out + S4));

  // Host-side dict-order fingerprint. in_sizes[17]==WLEN discriminates dict vs signature order
  // (signature order would have w2=1024 at slot 17). Failure -> absmax exactly 3.0625 (stub sig).
  bool ok = (n_in >= 29) && out_size == 2 * S4 && ws_size >= WS_NEED;
  if (ok) {
    const int big[2] = {0, 1};
    for (int i = 0; i < 2; ++i) ok = ok && (in_sizes[big[i]] == S4);
    const int w1m[9] = {11, 12, 13, 14, 15, 16, 17, 18, 19};
    for (int i = 0; i < 9; ++i) ok = ok && (in_sizes[w1m[i]] == WLEN);
    const int sml[18] = {2, 3, 4, 5, 6, 7, 8, 9, 10, 20, 21, 22, 23, 24, 25, 26, 27, 28};
    for (int i = 0; i < 18; ++i) ok = ok && (in_sizes[sml[i]] == 1024);
  }
  if (!ok) {
    k_fill0<<<16384, 256, 0, stream>>>((float*)d_out);
    return;
  }

  char* ws = (char*)d_ws;
  float* SR = (float*)(ws + OFF_SR);
  float* Gb = (float*)(ws + OFF_G);
  float* Yb = (float*)(ws + OFF_Y);
  float* Yg = (float*)(ws + OFF_YG);
  const float* x = (const float*)d_in[0];

  // 7 projections with fused time-shift mix. dict idx: 2..7 = x_r,x_w,x_k,x_v,x_a,x_g;
  // 11:Wr 12:Wk 13:Wv 14:Wg(unused) 15:Wo 16:Ww1 17:Wa1 18:Wv1 19:Wg1
  const int ci[7] = {2, 3, 4, 5, 5, 6, 7};        // xr xw xk xv xv xa xg
  const int wi[7] = {11, 16, 12, 13, 18, 17, 19}; // Wr Ww1 Wk Wv Wv1 Wa1 Wg1
  for (int z = 0; z < 7; ++z)
    k_gemmf<1><<<dim3(64, 256), 256, 0, stream>>>(x, (const float*)d_in[ci[z]],
                                                  (const float*)d_in[wi[z]], Gb + (size_t)z * S4);

  // params: 8:w0 9:a0 10:v0 20:w2 21:a2 22:v2 23:g2 24:k_k 25:k_a 26:r_k 27:ln_w 28:ln_b
  k_elem<<<16384, 256, 0, stream>>>(Gb, (const float*)d_in[1],
                                    (const float*)d_in[8], (const float*)d_in[20],
                                    (const float*)d_in[9], (const float*)d_in[21],
                                    (const float*)d_in[10], (const float*)d_in[22],
                                    (const float*)d_in[23], (const float*)d_in[24],
                                    (const float*)d_in[25], (const float*)d_in[26], SR);

  k_scan<<<256, 64, 0, stream>>>(Gb, Yb);
  k_post<<<16384, 256, 0, stream>>>(Yb, Gb, (const float*)d_in[27], (const float*)d_in[28], SR, Yg);

  // final projection: out0 = Yg @ Wo^T (no shift)
  k_gemmf<0><<<dim3(64, 256), 256, 0, stream>>>(Yg, nullptr, (const float*)d_in[15], (float*)d_out);
}